// Round 1
// baseline (318.088 us; speedup 1.0000x reference)
//
#include <hip/hip_runtime.h>
#include <hip/hip_bf16.h>

#define NB 16384     // rows (B)
#define NC 1000      // classes (C)
#define NV (NC / 4)  // float4 loads per row = 250

__global__ void zero_out_kernel(float* out) {
    out[0] = 0.0f;
}

__global__ __launch_bounds__(256) void ranking_loss_kernel(
        const float* __restrict__ logits,
        const float* __restrict__ target,
        float* __restrict__ out) {
    const int row  = blockIdx.x;
    const int t    = threadIdx.x;
    const int wave = t >> 6;
    const int lane = t & 63;

    const float* __restrict__ trow = target + (size_t)row * NC;
    const float* __restrict__ lrow = logits + (size_t)row * NC;

    // ---- issue both global loads up front (overlap latency) ----
    float4 tv = make_float4(0.f, 0.f, 0.f, 0.f);
    float4 lv = make_float4(0.f, 0.f, 0.f, 0.f);
    const bool active = (t < NV);
    if (active) {
        tv = ((const float4*)trow)[t];
        lv = ((const float4*)lrow)[t];
    }

    // ---- phase 1: argmax(target row), first-index tie-break ----
    float bv = -INFINITY;
    int   bi = NC;  // sentinel > any valid index
    if (active) {
        const int base = t * 4;
        float vals[4] = {tv.x, tv.y, tv.z, tv.w};
        #pragma unroll
        for (int k = 0; k < 4; ++k) {
            if (vals[k] > bv) { bv = vals[k]; bi = base + k; }
        }
    }
    #pragma unroll
    for (int off = 32; off > 0; off >>= 1) {
        float ov = __shfl_down(bv, off, 64);
        int   oi = __shfl_down(bi, off, 64);
        if (ov > bv || (ov == bv && oi < bi)) { bv = ov; bi = oi; }
    }

    __shared__ float s_v[4];
    __shared__ int   s_i[4];
    __shared__ int   s_label;
    __shared__ float s_x1;
    if (lane == 0) { s_v[wave] = bv; s_i[wave] = bi; }
    __syncthreads();
    if (t == 0) {
        float mv = s_v[0]; int mi = s_i[0];
        #pragma unroll
        for (int w = 1; w < 4; ++w) {
            if (s_v[w] > mv || (s_v[w] == mv && s_i[w] < mi)) { mv = s_v[w]; mi = s_i[w]; }
        }
        s_label = mi;
        s_x1 = lrow[mi];   // row is hot in L1/L2
    }
    __syncthreads();
    const int   label = s_label;
    const float x1    = s_x1;

    // ---- phase 2: sum of hinge terms (from registers already loaded) ----
    const float inv_pos = 1.0f / (float)(NC - 1);
    float sum = 0.0f;
    if (active) {
        const int base = t * 4;
        float vals[4] = {lv.x, lv.y, lv.z, lv.w};
        #pragma unroll
        for (int k = 0; k < 4; ++k) {
            const int j = base + k;
            // j==0: neg term, margin = 1.0 (NEG_MARGIN * relu(...), NEG_MARGIN = 1)
            const float margin = (j == 0) ? 1.0f
                                          : fabsf((float)(label - j)) * inv_pos;
            sum += fmaxf(vals[k] - x1 + margin, 0.0f);
        }
    }
    #pragma unroll
    for (int off = 32; off > 0; off >>= 1)
        sum += __shfl_down(sum, off, 64);

    __shared__ float s_sum[4];
    if (lane == 0) s_sum[wave] = sum;
    __syncthreads();
    if (t == 0) {
        const float tot = s_sum[0] + s_sum[1] + s_sum[2] + s_sum[3];
        if (label != 0)
            atomicAdd(out, tot * (1.0f / (float)NB));
    }
}

extern "C" void kernel_launch(void* const* d_in, const int* in_sizes, int n_in,
                              void* d_out, int out_size, void* d_ws, size_t ws_size,
                              hipStream_t stream) {
    const float* logits = (const float*)d_in[0];
    const float* target = (const float*)d_in[1];
    float* out = (float*)d_out;

    // d_out is re-poisoned to 0xAA before every timed replay -> zero it on-stream.
    zero_out_kernel<<<1, 1, 0, stream>>>(out);
    ranking_loss_kernel<<<NB, 256, 0, stream>>>(logits, target, out);
}

// Round 2
// 141.910 us; speedup vs baseline: 2.2415x; 2.2415x over previous
//
#include <hip/hip_runtime.h>
#include <hip/hip_bf16.h>

#define NB 16384     // rows (B)
#define NC 1000      // classes (C)
#define NV (NC / 4)  // float4 loads per row = 250

__global__ __launch_bounds__(256) void ranking_loss_kernel(
        const float* __restrict__ logits,
        const float* __restrict__ target,
        float* __restrict__ partial) {
    const int row  = blockIdx.x;
    const int t    = threadIdx.x;
    const int wave = t >> 6;
    const int lane = t & 63;

    const float* __restrict__ trow = target + (size_t)row * NC;
    const float* __restrict__ lrow = logits + (size_t)row * NC;

    // ---- issue both global loads up front (overlap latency) ----
    float4 tv = make_float4(0.f, 0.f, 0.f, 0.f);
    float4 lv = make_float4(0.f, 0.f, 0.f, 0.f);
    const bool active = (t < NV);
    if (active) {
        tv = ((const float4*)trow)[t];
        lv = ((const float4*)lrow)[t];
    }

    // ---- phase 1: argmax(target row), first-index tie-break ----
    float bv = -INFINITY;
    int   bi = NC;  // sentinel > any valid index
    if (active) {
        const int base = t * 4;
        float vals[4] = {tv.x, tv.y, tv.z, tv.w};
        #pragma unroll
        for (int k = 0; k < 4; ++k) {
            if (vals[k] > bv) { bv = vals[k]; bi = base + k; }
        }
    }
    #pragma unroll
    for (int off = 32; off > 0; off >>= 1) {
        float ov = __shfl_down(bv, off, 64);
        int   oi = __shfl_down(bi, off, 64);
        if (ov > bv || (ov == bv && oi < bi)) { bv = ov; bi = oi; }
    }

    __shared__ float s_v[4];
    __shared__ int   s_i[4];
    __shared__ int   s_label;
    __shared__ float s_x1;
    if (lane == 0) { s_v[wave] = bv; s_i[wave] = bi; }
    __syncthreads();
    if (t == 0) {
        float mv = s_v[0]; int mi = s_i[0];
        #pragma unroll
        for (int w = 1; w < 4; ++w) {
            if (s_v[w] > mv || (s_v[w] == mv && s_i[w] < mi)) { mv = s_v[w]; mi = s_i[w]; }
        }
        s_label = mi;
        s_x1 = lrow[mi];   // row is hot in L1/L2
    }
    __syncthreads();
    const int   label = s_label;
    const float x1    = s_x1;

    // ---- phase 2: sum of hinge terms (from registers already loaded) ----
    const float inv_pos = 1.0f / (float)(NC - 1);
    float sum = 0.0f;
    if (active) {
        const int base = t * 4;
        float vals[4] = {lv.x, lv.y, lv.z, lv.w};
        #pragma unroll
        for (int k = 0; k < 4; ++k) {
            const int j = base + k;
            // j==0: neg term, margin = 1.0 (NEG_MARGIN * relu(...), NEG_MARGIN = 1)
            const float margin = (j == 0) ? 1.0f
                                          : fabsf((float)(label - j)) * inv_pos;
            sum += fmaxf(vals[k] - x1 + margin, 0.0f);
        }
    }
    #pragma unroll
    for (int off = 32; off > 0; off >>= 1)
        sum += __shfl_down(sum, off, 64);

    __shared__ float s_sum[4];
    if (lane == 0) s_sum[wave] = sum;
    __syncthreads();
    if (t == 0) {
        const float tot = s_sum[0] + s_sum[1] + s_sum[2] + s_sum[3];
        // plain coalesced store, no atomic; pre-scale by 1/B
        partial[row] = (label != 0) ? tot * (1.0f / (float)NB) : 0.0f;
    }
}

// Sum 16384 partials -> out[0]. One block, 256 threads, float4 loads.
__global__ __launch_bounds__(256) void reduce_partials_kernel(
        const float* __restrict__ partial,
        float* __restrict__ out) {
    const int t    = threadIdx.x;
    const int wave = t >> 6;
    const int lane = t & 63;

    float sum = 0.0f;
    const float4* p4 = (const float4*)partial;
    // NB/4 = 4096 float4; 256 threads -> 16 each, coalesced stride
    #pragma unroll
    for (int i = 0; i < 16; ++i) {
        float4 v = p4[t + i * 256];
        sum += (v.x + v.y) + (v.z + v.w);
    }
    #pragma unroll
    for (int off = 32; off > 0; off >>= 1)
        sum += __shfl_down(sum, off, 64);

    __shared__ float s_sum[4];
    if (lane == 0) s_sum[wave] = sum;
    __syncthreads();
    if (t == 0)
        out[0] = s_sum[0] + s_sum[1] + s_sum[2] + s_sum[3];
}

extern "C" void kernel_launch(void* const* d_in, const int* in_sizes, int n_in,
                              void* d_out, int out_size, void* d_ws, size_t ws_size,
                              hipStream_t stream) {
    const float* logits = (const float*)d_in[0];
    const float* target = (const float*)d_in[1];
    float* out     = (float*)d_out;
    float* partial = (float*)d_ws;   // NB floats = 64 KB scratch

    ranking_loss_kernel<<<NB, 256, 0, stream>>>(logits, target, partial);
    reduce_partials_kernel<<<1, 256, 0, stream>>>(partial, out);
}